// Round 6
// baseline (63862.488 us; speedup 1.0000x reference)
//
#include <hip/hip_runtime.h>
#include <math.h>

// Problem constants
#define BB 64
#define SS 512
#define EE 256
#define HH 512
#define HD 1024
#define TT 9
#define MM (BB*SS)

typedef __attribute__((ext_vector_type(8))) short      short8;   // 8 bf16
typedef __attribute__((ext_vector_type(4))) float      f32x4;
typedef __attribute__((ext_vector_type(4))) unsigned   uint4v;

__device__ __forceinline__ unsigned short f2bfu(float x) {
    unsigned b = __float_as_uint(x);
    b += 0x7FFFu + ((b >> 16) & 1u);      // RNE
    return (unsigned short)(b >> 16);
}
__device__ __forceinline__ unsigned pack2bf(float lo, float hi) {
    return ((unsigned)f2bfu(hi) << 16) | (unsigned)f2bfu(lo);
}

// ---------------------------------------------------------------------------
__global__ void zero_kernel(float* __restrict__ p, int n)
{
    int i = blockIdx.x * blockDim.x + threadIdx.x;
    int stride = gridDim.x * blockDim.x;
    for (; i < n; i += stride) p[i] = 0.f;
}

// ---------------------------------------------------------------------------
// Pack [w_ih | w_hh] (fp32) into MFMA-A-fragment-linear bf16 (validated r4/5):
// dst[tid], tid = ((((d*16+jb)*nch + ch)*16 + fr)*64 + lane)*8 + j
// fr = ksl*8 + mt; A-element: row r = mt*16 + (lane&15) -> gate q=r>>5, jj=r&31
// packed k = ch*64 + ksl*32 + (lane>>4)*8 + j;  k<KX -> w_ih else w_hh.
// ---------------------------------------------------------------------------
__global__ void pack_kernel(const float* __restrict__ w_ih, const float* __restrict__ w_hh,
                            unsigned short* __restrict__ dst, int KX, int nch, int total)
{
    int tid = blockIdx.x * 256 + threadIdx.x;
    if (tid >= total) return;
    int u = tid;
    int j    = u & 7;  u >>= 3;
    int lane = u & 63; u >>= 6;
    int fr   = u & 15; u >>= 4;
    int ch   = u % nch; u /= nch;
    int jb   = u & 15; u >>= 4;
    int d    = u;
    int ksl = fr >> 3, mt = fr & 7;
    int quad = lane >> 4, m = lane & 15;
    int r = mt * 16 + m;
    int q = r >> 5, jj = r & 31;
    int row = q * HH + jb * 32 + jj;
    int kp  = ch * 64 + ksl * 32 + quad * 8 + j;
    float v;
    if (kp < KX) v = w_ih[((size_t)d * 2048 + row) * (size_t)KX + kp];
    else         v = w_hh[((size_t)d * 2048 + row) * (size_t)HH + (kp - KX)];
    dst[tid] = f2bfu(v);
}

// ---------------------------------------------------------------------------
// Persistent BiLSTM layer, registers-only K-loop (round-6 restructure).
// 32 blocks x 256 threads (4 waves), all resident. bid>>4 = dir, bid&15 = jb
// (32 hidden units). Wave wv owns 16 batches (b = wv*16 + lane&15); full K per
// wave -> NO cross-wave reduction, NO LDS, NO in-loop __syncthreads.
// A fragments are contiguous 16B in frag-linear packA -> loaded STRAIGHT to
// VGPRs, double-buffered one chunk ahead; B fragments likewise. The compiler
// then emits fine-grained per-register s_waitcnt vmcnt(N) instead of the
// vmcnt(0) barrier drains that serialized rounds 4/5 (per-chunk latency
// exposure ~54us/step at MfmaUtil 0.6%).
// Step barrier: relaxed agent-scope atomics (r5-validated); h data via
// MALL-coherent relaxed atomic u64 loads/stores.
// ---------------------------------------------------------------------------
template<int LAYER>
__global__ __launch_bounds__(256, 1)
void bilstm_persist(const int* __restrict__ ids, const float* __restrict__ emb,
                    const unsigned short* __restrict__ x1,
                    const unsigned short* __restrict__ packA,
                    const float* __restrict__ b_ih, const float* __restrict__ b_hh,
                    const float* __restrict__ cls_w,
                    unsigned short* hbuf,                // [2 dir][2 ping][64][512] bf16
                    unsigned short* __restrict__ h0out,  // layer0 out (bf16)
                    float* __restrict__ plog,            // [32][64][512][9]
                    unsigned* cnt)
{
    constexpr int KX  = LAYER ? HD : EE;
    constexpr int NCH = (KX + HH) / 64;
    constexpr int XCH = KX / 64;

    const int bid  = blockIdx.x;
    const int d    = bid >> 4;
    const int jb   = bid & 15;
    const int tid  = threadIdx.x;
    const int lane = tid & 63;
    const int wv   = tid >> 6;
    const int quad = lane >> 4;
    const int ln15 = lane & 15;
    const int b    = wv * 16 + ln15;          // this lane's batch

    const unsigned short* myA = packA + (size_t)((d * 16 + jb) * NCH) * 8192;

    float bias_[4][2][4];
    #pragma unroll
    for (int q = 0; q < 4; q++)
        #pragma unroll
        for (int hi = 0; hi < 2; hi++)
            #pragma unroll
            for (int i = 0; i < 4; i++) {
                int jj  = hi * 16 + quad * 4 + i;
                int row = d * 2048 + q * HH + jb * 32 + jj;
                bias_[q][hi][i] = b_ih[row] + b_hh[row];
            }

    float clsw[8][TT];
    if (LAYER == 1) {
        #pragma unroll
        for (int hi = 0; hi < 2; hi++)
            #pragma unroll
            for (int i = 0; i < 4; i++) {
                int jj = hi * 16 + quad * 4 + i;
                #pragma unroll
                for (int n = 0; n < TT; n++)
                    clsw[hi * 4 + i][n] = cls_w[n * HD + d * HH + jb * 32 + jj];
            }
    }

    float  c_[2][4] = {};                     // [hi][i]
    uint4v Ar[2][16];                         // A double buffer (128 VGPR)
    uint4v Br[2][2];                          // B double buffer  (16 VGPR)
    f32x4  acc[8];

    for (int s = 0; s < SS; s++) {
        const int t = d ? (SS - 1 - s) : s;
        const int p = s & 1;

        #pragma unroll
        for (int mt = 0; mt < 8; mt++) acc[mt] = f32x4{0.f, 0.f, 0.f, 0.f};

        // per-step source rows for B (x part)
        const float*          erow = nullptr;
        const unsigned short* xrow = nullptr;
        if (LAYER == 0) erow = emb + (size_t)ids[b * SS + t] * EE + quad * 8;
        else            xrow = x1 + ((size_t)(b * SS + t)) * HD + quad * 8;

        auto loadA = [&](int ch, int buf) {
            const uint4v* src = (const uint4v*)(myA + (size_t)ch * 8192);
            #pragma unroll
            for (int f = 0; f < 16; f++) Ar[buf][f] = src[f * 64 + lane];
        };
        auto loadBx = [&](int ch, int buf) {
            if (LAYER == 0) {
                #pragma unroll
                for (int ksl = 0; ksl < 2; ksl++) {
                    float4 f0 = *(const float4*)(erow + ch * 64 + ksl * 32);
                    float4 f1 = *(const float4*)(erow + ch * 64 + ksl * 32 + 4);
                    uint4v u;
                    u[0] = pack2bf(f0.x, f0.y); u[1] = pack2bf(f0.z, f0.w);
                    u[2] = pack2bf(f1.x, f1.y); u[3] = pack2bf(f1.z, f1.w);
                    Br[buf][ksl] = u;
                }
            } else {
                Br[buf][0] = *(const uint4v*)(xrow + ch * 64);
                Br[buf][1] = *(const uint4v*)(xrow + ch * 64 + 32);
            }
        };
        auto loadBh = [&](int ch, int buf) {
            const unsigned long long* hp = (const unsigned long long*)
                (hbuf + ((size_t)((d * 2 + p) * BB + b)) * HH + (ch - XCH) * 64 + quad * 8);
            #pragma unroll
            for (int ksl = 0; ksl < 2; ksl++) {
                unsigned long long l0 = __hip_atomic_load(hp + ksl * 8,
                                          __ATOMIC_RELAXED, __HIP_MEMORY_SCOPE_AGENT);
                unsigned long long l1 = __hip_atomic_load(hp + ksl * 8 + 1,
                                          __ATOMIC_RELAXED, __HIP_MEMORY_SCOPE_AGENT);
                uint4v u;
                u[0] = (unsigned)l0; u[1] = (unsigned)(l0 >> 32);
                u[2] = (unsigned)l1; u[3] = (unsigned)(l1 >> 32);
                Br[buf][ksl] = u;
            }
        };
        auto domfma = [&](int buf) {
            #pragma unroll
            for (int ksl = 0; ksl < 2; ksl++) {
                short8 bf = __builtin_bit_cast(short8, Br[buf][ksl]);
                #pragma unroll
                for (int mt = 0; mt < 8; mt++) {
                    short8 a = __builtin_bit_cast(short8, Ar[buf][ksl * 8 + mt]);
                    acc[mt] = __builtin_amdgcn_mfma_f32_16x16x32_bf16(a, bf, acc[mt], 0, 0, 0);
                }
            }
        };

        // ---- x-projection (independent of other blocks; hides barrier) ----
        loadA(0, 0); loadBx(0, 0);
        #pragma unroll
        for (int ch = 0; ch < XCH; ch++) {
            const int buf = ch & 1;
            if (ch + 1 < XCH) { loadA(ch + 1, buf ^ 1); loadBx(ch + 1, buf ^ 1); }
            domfma(buf);
        }

        // ---- wait for step s-1's h (16 blocks per dir) ----
        if (tid == 0) {
            const unsigned tgt = 16u * (unsigned)s;
            while (__hip_atomic_load(&cnt[d], __ATOMIC_RELAXED,
                                     __HIP_MEMORY_SCOPE_AGENT) < tgt)
                __builtin_amdgcn_s_sleep(1);
        }
        __atomic_signal_fence(__ATOMIC_ACQ_REL);
        __syncthreads();

        // ---- h-recurrence ----
        loadA(XCH, XCH & 1); loadBh(XCH, XCH & 1);
        #pragma unroll
        for (int ch = XCH; ch < NCH; ch++) {
            const int buf = ch & 1;
            if (ch + 1 < NCH) { loadA(ch + 1, buf ^ 1); loadBh(ch + 1, buf ^ 1); }
            domfma(buf);
        }

        // ---- epilogue: lane owns batch b x 8 units (jj = hi*16+quad*4+i) ----
        float pl[TT];
        if (LAYER == 1) {
            #pragma unroll
            for (int n = 0; n < TT; n++) pl[n] = 0.f;
        }
        #pragma unroll
        for (int hi = 0; hi < 2; hi++) {
            unsigned hp0 = 0, hp1 = 0;
            #pragma unroll
            for (int i = 0; i < 4; i++) {
                float gi = acc[0 + hi][i] + bias_[0][hi][i];
                float gf = acc[2 + hi][i] + bias_[1][hi][i];
                float gg = acc[4 + hi][i] + bias_[2][hi][i];
                float go = acc[6 + hi][i] + bias_[3][hi][i];
                float i_ = 1.f / (1.f + __expf(-gi));
                float f_ = 1.f / (1.f + __expf(-gf));
                float xg = fminf(fmaxf(gg, -15.f), 15.f);
                float e2 = __expf(2.f * xg);
                float g_ = (e2 - 1.f) / (e2 + 1.f);
                float o_ = 1.f / (1.f + __expf(-go));
                float cc = f_ * c_[hi][i] + i_ * g_;
                c_[hi][i] = cc;
                float xc  = fminf(fmaxf(cc, -15.f), 15.f);
                float e2c = __expf(2.f * xc);
                float th  = (e2c - 1.f) / (e2c + 1.f);
                float hn  = o_ * th;
                if (i < 2) hp0 |= (unsigned)f2bfu(hn) << (16 * i);
                else       hp1 |= (unsigned)f2bfu(hn) << (16 * (i - 2));
                if (LAYER == 1) {
                    #pragma unroll
                    for (int n = 0; n < TT; n++) pl[n] += hn * clsw[hi * 4 + i][n];
                }
            }
            unsigned long long hv = ((unsigned long long)hp1 << 32) | hp0;
            const int joff = jb * 32 + hi * 16 + quad * 4;
            __hip_atomic_store((unsigned long long*)
                (hbuf + ((size_t)((d * 2 + (p ^ 1)) * BB + b)) * HH + joff),
                hv, __ATOMIC_RELAXED, __HIP_MEMORY_SCOPE_AGENT);
            if (LAYER == 0)
                *(unsigned long long*)(h0out + ((size_t)(b * SS + t)) * HD + d * HH + joff) = hv;
        }
        if (LAYER == 1) {
            #pragma unroll
            for (int n = 0; n < TT; n++) {
                float v = pl[n];
                v += __shfl_xor(v, 16);
                v += __shfl_xor(v, 32);
                pl[n] = v;
            }
            if (quad == 0) {
                float* dstp = plog + (((size_t)(d * 16 + jb) * BB + b) * SS + t) * TT;
                #pragma unroll
                for (int n = 0; n < TT; n++) dstp[n] = pl[n];
            }
        }
        // arrive: __syncthreads() emits s_waitcnt vmcnt(0) per wave before
        // s_barrier -> all waves' h stores are at the MALL before the add.
        __syncthreads();
        __atomic_signal_fence(__ATOMIC_ACQ_REL);
        if (tid == 0)
            __hip_atomic_fetch_add(&cnt[d], 1u, __ATOMIC_RELAXED, __HIP_MEMORY_SCOPE_AGENT);
    }
}

// ---------------------------------------------------------------------------
// logits[i] = sum over 32 (dir,jb) partials  (cls_b added in CRF kernel)
// ---------------------------------------------------------------------------
__global__ void reduce_logits(const float* __restrict__ plog, float* __restrict__ out)
{
    int i = blockIdx.x * 256 + threadIdx.x;
    if (i >= MM * TT) return;
    float s = 0.f;
    #pragma unroll
    for (int g = 0; g < 32; g++) s += plog[(size_t)g * (MM * TT) + i];
    out[i] = s;
}

// ---------------------------------------------------------------------------
// CRF viterbi + loss (validated rounds 2-5). cls_b folded here.
// ---------------------------------------------------------------------------
__global__ __launch_bounds__(64)
void crf_kernel(const float* __restrict__ logits, const int* __restrict__ labels,
                const int* __restrict__ vlens, const float* __restrict__ trans,
                const float* __restrict__ start_t, const float* __restrict__ end_t,
                const float* __restrict__ cls_b,
                float* __restrict__ tags_out, float* __restrict__ llh)
{
    const int b = blockIdx.x;
    const int lane = threadIdx.x;
    const int len = vlens[b];
    const float* em = logits + (size_t)b * (SS * TT);
    const int*  lab = labels + (size_t)b * SS;
    __shared__ unsigned char hist[(SS - 1) * TT];

    float cb = (lane < TT) ? cls_b[lane] : 0.f;
    float tcol[TT];
    #pragma unroll
    for (int i = 0; i < TT; i++) tcol[i] = (lane < TT) ? trans[i * TT + lane] : 0.f;
    float score = (lane < TT) ? (start_t[lane] + em[lane] + cb) : 0.f;
    float alpha = score;
    float num = 0.f; int plab = 0;
    if (lane == 0) { plab = lab[0]; num = start_t[plab] + em[plab] + cls_b[plab]; }

    for (int t = 1; t < SS; t++) {
        float emj = (lane < TT) ? (em[t * TT + lane] + cb) : 0.f;
        float sv[TT], av[TT];
        #pragma unroll
        for (int i = 0; i < TT; i++) { sv[i] = __shfl(score, i); av[i] = __shfl(alpha, i); }
        float best = -INFINITY; int bp = 0; float amx = -INFINITY;
        #pragma unroll
        for (int i = 0; i < TT; i++) {
            float cnd = sv[i] + tcol[i];
            if (cnd > best) { best = cnd; bp = i; }   // strict >: FIRST max
            amx = fmaxf(amx, av[i] + tcol[i]);
        }
        float se = 0.f;
        #pragma unroll
        for (int i = 0; i < TT; i++) se += expf(av[i] + tcol[i] - amx);
        const bool m = (t < len);
        if (m) { score = best + emj; alpha = amx + logf(se) + emj; }
        if (lane < TT) hist[(t - 1) * TT + lane] = (unsigned char)bp;
        if (lane == 0 && m) {
            int lt = lab[t];
            num += em[t * TT + lt] + cls_b[lt] + trans[plab * TT + lt];
            plab = lt;
        }
    }
    float fsc[TT], fal[TT];
    #pragma unroll
    for (int i = 0; i < TT; i++) { fsc[i] = __shfl(score, i); fal[i] = __shfl(alpha, i); }
    __syncthreads();
    if (lane == 0) {
        num += end_t[lab[len - 1]];
        int bl = 0; float bv = fsc[0] + end_t[0];
        #pragma unroll
        for (int i = 1; i < TT; i++) {
            float v = fsc[i] + end_t[i];
            if (v > bv) { bv = v; bl = i; }
        }
        float zmx = -INFINITY;
        #pragma unroll
        for (int i = 0; i < TT; i++) zmx = fmaxf(zmx, fal[i] + end_t[i]);
        float zse = 0.f;
        #pragma unroll
        for (int i = 0; i < TT; i++) zse += expf(fal[i] + end_t[i] - zmx);
        llh[b] = num - (zmx + logf(zse));
        int tag = bl;
        tags_out[b * SS + (SS - 1)] = (float)tag;
        for (int t = SS - 2; t >= 0; t--) {
            if (t + 1 < len) tag = hist[t * TT + tag];
            tags_out[b * SS + t] = (float)tag;
        }
    }
}

__global__ void loss_kernel(const float* __restrict__ llh, float* __restrict__ out)
{
    float v = llh[threadIdx.x];
    #pragma unroll
    for (int off = 32; off > 0; off >>= 1) v += __shfl_down(v, off);
    if (threadIdx.x == 0) out[MM] = -(v / 64.f);
}

// ---------------------------------------------------------------------------
extern "C" void kernel_launch(void* const* d_in, const int* in_sizes, int n_in,
                              void* d_out, int out_size, void* d_ws, size_t ws_size,
                              hipStream_t stream)
{
    const int*   ids     = (const int*)  d_in[0];
    const int*   vlen    = (const int*)  d_in[1];
    const int*   labels  = (const int*)  d_in[2];
    const float* emb     = (const float*)d_in[3];
    const float* w_ih0   = (const float*)d_in[4];
    const float* w_hh0   = (const float*)d_in[5];
    const float* b_ih0   = (const float*)d_in[6];
    const float* b_hh0   = (const float*)d_in[7];
    const float* w_ih1   = (const float*)d_in[8];
    const float* w_hh1   = (const float*)d_in[9];
    const float* b_ih1   = (const float*)d_in[10];
    const float* b_hh1   = (const float*)d_in[11];
    const float* cls_w   = (const float*)d_in[12];
    const float* cls_b   = (const float*)d_in[13];
    const float* trans   = (const float*)d_in[14];
    const float* start_t = (const float*)d_in[15];
    const float* end_t   = (const float*)d_in[16];

    // Workspace (~125 MB):
    // [logits 1.18MB][llh][cnt 16u32][hbuf0 256KB][hbuf1 256KB][h0out 64MB]
    // [packA0 6MB][packA1 12MB][plog 37.7MB]
    float*          logits = (float*)d_ws;
    float*          llh    = logits + (size_t)MM * TT;
    unsigned*       cnt    = (unsigned*)(llh + 64);
    unsigned short* hbuf0  = (unsigned short*)(cnt + 16);
    unsigned short* hbuf1  = hbuf0 + 131072;
    unsigned short* h0out  = hbuf1 + 131072;
    unsigned short* packA0 = h0out + (size_t)MM * HD;
    unsigned short* packA1 = packA0 + 3145728;
    float*          plog   = (float*)(packA1 + 6291456);

    // zero: cnt(64B) + hbuf0 + hbuf1 = 16 + 131072 floats
    zero_kernel<<<512, 256, 0, stream>>>((float*)cnt, 16 + (131072 + 131072) / 2);

    pack_kernel<<<(3145728 + 255) / 256, 256, 0, stream>>>(w_ih0, w_hh0, packA0, EE, 12, 3145728);
    pack_kernel<<<(6291456 + 255) / 256, 256, 0, stream>>>(w_ih1, w_hh1, packA1, HD, 24, 6291456);

    bilstm_persist<0><<<32, 256, 0, stream>>>(
        ids, emb, nullptr, packA0, b_ih0, b_hh0, nullptr, hbuf0, h0out, nullptr, cnt);
    bilstm_persist<1><<<32, 256, 0, stream>>>(
        ids, nullptr, h0out, packA1, b_ih1, b_hh1, cls_w, hbuf1, nullptr, plog, cnt + 2);

    reduce_logits<<<(MM * TT + 255) / 256, 256, 0, stream>>>(plog, logits);
    crf_kernel<<<BB, 64, 0, stream>>>(logits, labels, vlen, trans, start_t, end_t,
                                      cls_b, (float*)d_out, llh);
    loss_kernel<<<1, 64, 0, stream>>>(llh, (float*)d_out);
}

// Round 7
// 10419.828 us; speedup vs baseline: 6.1289x; 6.1289x over previous
//
#include <hip/hip_runtime.h>
#include <hip/hip_fp8.h>
#include <math.h>

// Problem constants
#define BB 64
#define SS 512
#define EE 256
#define HH 512
#define HD 1024
#define TT 9
#define MM (BB*SS)

typedef __attribute__((ext_vector_type(8))) short    short8;   // 8 bf16
typedef __attribute__((ext_vector_type(4))) float    f32x4;
typedef __attribute__((ext_vector_type(4))) unsigned uint4v;

__device__ __forceinline__ unsigned short f2bfu(float x) {
    unsigned b = __float_as_uint(x);
    b += 0x7FFFu + ((b >> 16) & 1u);      // RNE
    return (unsigned short)(b >> 16);
}
__device__ __forceinline__ unsigned pack2bf(float lo, float hi) {
    return ((unsigned)f2bfu(hi) << 16) | (unsigned)f2bfu(lo);
}

// ---------------------------------------------------------------------------
__global__ void zero_kernel(float* __restrict__ p, int n)
{
    int i = blockIdx.x * blockDim.x + threadIdx.x;
    int stride = gridDim.x * blockDim.x;
    for (; i < n; i += stride) p[i] = 0.f;
}

// ---------------------------------------------------------------------------
// Pack [w_ih | w_hh] fp32 -> MFMA-A-frag-linear bf16, NJ=4 tiles (M=16).
// tid = ((((d*128+jb)*nf + f)*64 + lane)*8 + j
// A row m = lane&15, ordered m = jj*4 + q  (jj = unit 0..3, q = gate i,f,g,o)
// -> each lane's C rows (quad*4+i) give ALL 4 gates of unit jj=quad.
// k = f*32 + (lane>>4)*8 + j;  k<KX -> w_ih else w_hh.
// ---------------------------------------------------------------------------
__global__ void pack_kernel(const float* __restrict__ w_ih, const float* __restrict__ w_hh,
                            unsigned short* __restrict__ dst, int KX, int nf, int total)
{
    int tid = blockIdx.x * 256 + threadIdx.x;
    if (tid >= total) return;
    int j    = tid & 7;
    int lane = (tid >> 3) & 63;
    int f    = (tid >> 9) % nf;
    int rest = (tid >> 9) / nf;
    int jb   = rest & 127;
    int d    = rest >> 7;
    int m = lane & 15, quad = lane >> 4;
    int jj = m >> 2, q = m & 3;
    int row = q * HH + jb * 4 + jj;
    int k   = f * 32 + quad * 8 + j;
    float v;
    if (k < KX) v = w_ih[((size_t)d * 2048 + row) * (size_t)KX + k];
    else        v = w_hh[((size_t)d * 2048 + row) * (size_t)HH + (k - KX)];
    dst[tid] = f2bfu(v);
}

// ---------------------------------------------------------------------------
// Persistent BiLSTM layer, A-STATIONARY registers (round-7 restructure).
// 256 blocks x 256 threads, 1 block/CU, all resident. bid>>7 = dir,
// bid&127 = jb (4 hidden units). Wave wv owns 16 batches. A fragments for the
// FULL K loaded ONCE before the step loop (L0: 96 VGPR, L1: 192 VGPR) ->
// zero steady-state A traffic (round 6's 11 GB re-stream eliminated).
// Per step: x-part MFMAs (pre-barrier, overlaps sync), relaxed-atomic
// 128-block-per-dir barrier (r5-validated protocol: relaxed poll, relaxed
// fetch_add after __syncthreads' vmcnt(0) drain -> no cache invalidates),
// h-part: 32 relaxed u64 MALL loads in one burst + 16 MFMAs, epilogue is one
// h value per lane (batch, unit) -> pair/quad shuffle-packed stores.
// ---------------------------------------------------------------------------
template<int LAYER>
__global__ __launch_bounds__(256, 1)
void bilstm_persist(const int* __restrict__ ids, const float* __restrict__ emb,
                    const unsigned short* __restrict__ x1,   // L1 input = h0out bf16
                    const unsigned short* __restrict__ packA,
                    const float* __restrict__ b_ih, const float* __restrict__ b_hh,
                    unsigned short* hbuf,                 // [2dir][2ping][64][512] bf16
                    unsigned short* __restrict__ h0out,   // L0 out (bf16)
                    unsigned char*  __restrict__ h1out,   // L1 out (fp8 e4m3)
                    unsigned* cnt)                        // cnt[d*16]
{
    constexpr int KX = LAYER ? HD : EE;
    constexpr int NF = (KX + HH) / 32;    // total k-frags (L0 24, L1 48)
    constexpr int XF = KX / 32;           // x frags (8 / 32)
    constexpr int HF = HH / 32;           // 16
    constexpr int XG = XF / 8;            // x groups (1 / 4)

    const int bid  = blockIdx.x;
    const int d    = bid >> 7;
    const int jb   = bid & 127;
    const int tid  = threadIdx.x;
    const int lane = tid & 63;
    const int wv   = tid >> 6;
    const int quad = lane >> 4;
    const int ln15 = lane & 15;
    const int b    = wv * 16 + ln15;      // this lane's batch
    const int u    = jb * 4 + quad;       // this lane's hidden unit

    // ---- A stationary: load whole weight tile into VGPRs once ----
    const uint4v* myA = (const uint4v*)(packA + (size_t)(d * 128 + jb) * NF * 512);
    uint4v Ar[NF];
    #pragma unroll
    for (int f = 0; f < NF; f++) Ar[f] = myA[f * 64 + lane];

    float bias_[4];
    #pragma unroll
    for (int q = 0; q < 4; q++)
        bias_[q] = b_ih[d * 2048 + q * HH + u] + b_hh[d * 2048 + q * HH + u];

    unsigned* myc = cnt + d * 16;         // own 64B line per counter
    float c_ = 0.f;

    for (int s = 0; s < SS; s++) {
        const int t = d ? (SS - 1 - s) : s;
        const int p = s & 1;
        f32x4 acc = {0.f, 0.f, 0.f, 0.f};

        const float*          erow = nullptr;
        const unsigned short* xrow = nullptr;
        if (LAYER == 0) erow = emb + (size_t)ids[b * SS + t] * EE;
        else            xrow = x1 + ((size_t)(b * SS + t)) * HD;

        auto loadBx = [&](int f) -> uint4v {
            const int k0 = f * 32 + quad * 8;
            if (LAYER == 0) {
                float4 f0 = *(const float4*)(erow + k0);
                float4 f1 = *(const float4*)(erow + k0 + 4);
                uint4v r;
                r[0] = pack2bf(f0.x, f0.y); r[1] = pack2bf(f0.z, f0.w);
                r[2] = pack2bf(f1.x, f1.y); r[3] = pack2bf(f1.z, f1.w);
                return r;
            } else {
                return *(const uint4v*)(xrow + k0);
            }
        };

        // ---- x-projection (independent of other blocks; overlaps barrier) ----
        uint4v Bg[2][8];
        #pragma unroll
        for (int jx = 0; jx < 8; jx++) Bg[0][jx] = loadBx(jx);
        #pragma unroll
        for (int g = 0; g < XG; g++) {
            const int cur = g & 1;
            if (g + 1 < XG) {
                #pragma unroll
                for (int jx = 0; jx < 8; jx++)
                    Bg[cur ^ 1][jx] = loadBx((g + 1) * 8 + jx);
            }
            #pragma unroll
            for (int jx = 0; jx < 8; jx++) {
                short8 a  = __builtin_bit_cast(short8, Ar[g * 8 + jx]);
                short8 bv = __builtin_bit_cast(short8, Bg[cur][jx]);
                acc = __builtin_amdgcn_mfma_f32_16x16x32_bf16(a, bv, acc, 0, 0, 0);
            }
        }

        // ---- wait: all 128 blocks of dir d finished step s-1 ----
        if (tid == 0) {
            const unsigned tgt = 128u * (unsigned)s;
            while (__hip_atomic_load(myc, __ATOMIC_RELAXED,
                                     __HIP_MEMORY_SCOPE_AGENT) < tgt)
                __builtin_amdgcn_s_sleep(2);
        }
        __atomic_signal_fence(__ATOMIC_ACQ_REL);
        __syncthreads();

        // ---- h-recurrence: one burst of 32 MALL loads, then 16 MFMAs ----
        {
            const unsigned long long* hp = (const unsigned long long*)
                (hbuf + ((size_t)((d * 2 + p) * BB + b)) * HH);
            uint4v Bh[HF];
            #pragma unroll
            for (int f = 0; f < HF; f++) {
                unsigned long long l0 = __hip_atomic_load(hp + f * 8 + quad * 2,
                                          __ATOMIC_RELAXED, __HIP_MEMORY_SCOPE_AGENT);
                unsigned long long l1 = __hip_atomic_load(hp + f * 8 + quad * 2 + 1,
                                          __ATOMIC_RELAXED, __HIP_MEMORY_SCOPE_AGENT);
                uint4v r;
                r[0] = (unsigned)l0; r[1] = (unsigned)(l0 >> 32);
                r[2] = (unsigned)l1; r[3] = (unsigned)(l1 >> 32);
                Bh[f] = r;
            }
            #pragma unroll
            for (int f = 0; f < HF; f++) {
                short8 a  = __builtin_bit_cast(short8, Ar[XF + f]);
                short8 bv = __builtin_bit_cast(short8, Bh[f]);
                acc = __builtin_amdgcn_mfma_f32_16x16x32_bf16(a, bv, acc, 0, 0, 0);
            }
        }

        // ---- epilogue: lane owns (batch b, unit u); acc[i] = gate i (i,f,g,o) ----
        float gi = acc[0] + bias_[0];
        float gf = acc[1] + bias_[1];
        float gg = acc[2] + bias_[2];
        float go = acc[3] + bias_[3];
        float i_ = 1.f / (1.f + __expf(-gi));
        float f_ = 1.f / (1.f + __expf(-gf));
        float xg = fminf(fmaxf(gg, -15.f), 15.f);
        float e2 = __expf(2.f * xg);
        float g_ = (e2 - 1.f) / (e2 + 1.f);
        float o_ = 1.f / (1.f + __expf(-go));
        c_ = f_ * c_ + i_ * g_;
        float xc  = fminf(fmaxf(c_, -15.f), 15.f);
        float e2c = __expf(2.f * xc);
        float hn  = o_ * ((e2c - 1.f) / (e2c + 1.f));

        // bf16 pair-pack (units u,u+1 via lane^16 partner), store by quads 0,2
        int hb = (int)f2bfu(hn);
        int ob = __shfl_xor(hb, 16);
        if (!(quad & 1)) {
            unsigned v32 = (unsigned)(unsigned short)hb
                         | ((unsigned)(unsigned short)ob << 16);
            __hip_atomic_store((unsigned*)(hbuf +
                ((size_t)((d * 2 + (p ^ 1)) * BB + b)) * HH + u),
                v32, __ATOMIC_RELAXED, __HIP_MEMORY_SCOPE_AGENT);
            if (LAYER == 0)
                *(unsigned*)(h0out + ((size_t)(b * SS + t)) * HD + d * HH + u) = v32;
        }
        if (LAYER == 1) {
            // fp8 4-pack (units jb*4..jb*4+3), one u32 store by quad 0
            __hip_fp8_e4m3 f8(hn);
            int b8  = (int)f8.__x;
            int o8  = __shfl_xor(b8, 16);
            int pr  = (b8 & 0xff) | ((o8 & 0xff) << 8);
            int pr2 = __shfl_xor(pr, 32);
            if (quad == 0) {
                unsigned val = (unsigned)(pr & 0xffff) | ((unsigned)(pr2 & 0xffff) << 16);
                *(unsigned*)(h1out + ((size_t)(b * SS + t)) * HD + d * HH + jb * 4) = val;
            }
        }

        // arrive: __syncthreads() drains vmcnt (h stores reach MALL) first
        __syncthreads();
        __atomic_signal_fence(__ATOMIC_ACQ_REL);
        if (tid == 0)
            __hip_atomic_fetch_add(myc, 1u, __ATOMIC_RELAXED, __HIP_MEMORY_SCOPE_AGENT);
    }
}

// ---------------------------------------------------------------------------
// logits[row,n] = sum_k fp8(h1[row,k]) * cls_w[n,k]   (cls_b added in CRF)
// 1 wave per row, 4 rows per block; Wc in LDS, conflict-free lane-consecutive.
// ---------------------------------------------------------------------------
__global__ __launch_bounds__(256)
void logits_fp8(const unsigned char* __restrict__ h1, const float* __restrict__ cls_w,
                float* __restrict__ out)
{
    __shared__ float Wc[TT * HD];
    const int tid = threadIdx.x;
    for (int i = tid; i < TT * HD; i += 256) Wc[i] = cls_w[i];
    __syncthreads();
    const int lane = tid & 63;
    const int row  = blockIdx.x * 4 + (tid >> 6);
    const unsigned char* xr = h1 + (size_t)row * HD;
    float p[TT] = {};
    #pragma unroll
    for (int it = 0; it < 16; it++) {
        __hip_fp8_e4m3 f8; f8.__x = xr[it * 64 + lane];
        float xv = (float)f8;
        #pragma unroll
        for (int n = 0; n < TT; n++) p[n] += xv * Wc[n * HD + it * 64 + lane];
    }
    #pragma unroll
    for (int n = 0; n < TT; n++) {
        float v = p[n];
        #pragma unroll
        for (int off = 32; off > 0; off >>= 1) v += __shfl_down(v, off);
        if (lane == 0) out[(size_t)row * TT + n] = v;
    }
}

// ---------------------------------------------------------------------------
// CRF viterbi + loss (validated rounds 2-6). cls_b folded here.
// ---------------------------------------------------------------------------
__global__ __launch_bounds__(64)
void crf_kernel(const float* __restrict__ logits, const int* __restrict__ labels,
                const int* __restrict__ vlens, const float* __restrict__ trans,
                const float* __restrict__ start_t, const float* __restrict__ end_t,
                const float* __restrict__ cls_b,
                float* __restrict__ tags_out, float* __restrict__ llh)
{
    const int b = blockIdx.x;
    const int lane = threadIdx.x;
    const int len = vlens[b];
    const float* em = logits + (size_t)b * (SS * TT);
    const int*  lab = labels + (size_t)b * SS;
    __shared__ unsigned char hist[(SS - 1) * TT];

    float cb = (lane < TT) ? cls_b[lane] : 0.f;
    float tcol[TT];
    #pragma unroll
    for (int i = 0; i < TT; i++) tcol[i] = (lane < TT) ? trans[i * TT + lane] : 0.f;
    float score = (lane < TT) ? (start_t[lane] + em[lane] + cb) : 0.f;
    float alpha = score;
    float num = 0.f; int plab = 0;
    if (lane == 0) { plab = lab[0]; num = start_t[plab] + em[plab] + cls_b[plab]; }

    for (int t = 1; t < SS; t++) {
        float emj = (lane < TT) ? (em[t * TT + lane] + cb) : 0.f;
        float sv[TT], av[TT];
        #pragma unroll
        for (int i = 0; i < TT; i++) { sv[i] = __shfl(score, i); av[i] = __shfl(alpha, i); }
        float best = -INFINITY; int bp = 0; float amx = -INFINITY;
        #pragma unroll
        for (int i = 0; i < TT; i++) {
            float cnd = sv[i] + tcol[i];
            if (cnd > best) { best = cnd; bp = i; }   // strict >: FIRST max
            amx = fmaxf(amx, av[i] + tcol[i]);
        }
        float se = 0.f;
        #pragma unroll
        for (int i = 0; i < TT; i++) se += expf(av[i] + tcol[i] - amx);
        const bool m = (t < len);
        if (m) { score = best + emj; alpha = amx + logf(se) + emj; }
        if (lane < TT) hist[(t - 1) * TT + lane] = (unsigned char)bp;
        if (lane == 0 && m) {
            int lt = lab[t];
            num += em[t * TT + lt] + cls_b[lt] + trans[plab * TT + lt];
            plab = lt;
        }
    }
    float fsc[TT], fal[TT];
    #pragma unroll
    for (int i = 0; i < TT; i++) { fsc[i] = __shfl(score, i); fal[i] = __shfl(alpha, i); }
    __syncthreads();
    if (lane == 0) {
        num += end_t[lab[len - 1]];
        int bl = 0; float bv = fsc[0] + end_t[0];
        #pragma unroll
        for (int i = 1; i < TT; i++) {
            float v = fsc[i] + end_t[i];
            if (v > bv) { bv = v; bl = i; }
        }
        float zmx = -INFINITY;
        #pragma unroll
        for (int i = 0; i < TT; i++) zmx = fmaxf(zmx, fal[i] + end_t[i]);
        float zse = 0.f;
        #pragma unroll
        for (int i = 0; i < TT; i++) zse += expf(fal[i] + end_t[i] - zmx);
        llh[b] = num - (zmx + logf(zse));
        int tag = bl;
        tags_out[b * SS + (SS - 1)] = (float)tag;
        for (int t = SS - 2; t >= 0; t--) {
            if (t + 1 < len) tag = hist[t * TT + tag];
            tags_out[b * SS + t] = (float)tag;
        }
    }
}

__global__ void loss_kernel(const float* __restrict__ llh, float* __restrict__ out)
{
    float v = llh[threadIdx.x];
    #pragma unroll
    for (int off = 32; off > 0; off >>= 1) v += __shfl_down(v, off);
    if (threadIdx.x == 0) out[MM] = -(v / 64.f);
}

// ---------------------------------------------------------------------------
extern "C" void kernel_launch(void* const* d_in, const int* in_sizes, int n_in,
                              void* d_out, int out_size, void* d_ws, size_t ws_size,
                              hipStream_t stream)
{
    const int*   ids     = (const int*)  d_in[0];
    const int*   vlen    = (const int*)  d_in[1];
    const int*   labels  = (const int*)  d_in[2];
    const float* emb     = (const float*)d_in[3];
    const float* w_ih0   = (const float*)d_in[4];
    const float* w_hh0   = (const float*)d_in[5];
    const float* b_ih0   = (const float*)d_in[6];
    const float* b_hh0   = (const float*)d_in[7];
    const float* w_ih1   = (const float*)d_in[8];
    const float* w_hh1   = (const float*)d_in[9];
    const float* b_ih1   = (const float*)d_in[10];
    const float* b_hh1   = (const float*)d_in[11];
    const float* cls_w   = (const float*)d_in[12];
    const float* cls_b   = (const float*)d_in[13];
    const float* trans   = (const float*)d_in[14];
    const float* start_t = (const float*)d_in[15];
    const float* end_t   = (const float*)d_in[16];

    // Workspace (~109 MB, fits proven >=136.2 MB floor with margin):
    // [llh 256B][cnt 256B][hbuf0 256KB][hbuf1 256KB][h0out 64MB bf16]
    // [packA1 12MB | logits 1.18MB after L1][packA0 6MB | h1out 32MB fp8 after L0]
    float*          llh    = (float*)d_ws;
    unsigned*       cnt    = (unsigned*)(llh + 64);            // 64 u32: 4 lines
    unsigned short* hbuf0  = (unsigned short*)(cnt + 64);
    unsigned short* hbuf1  = hbuf0 + 131072;
    unsigned short* h0out  = hbuf1 + 131072;                   // MM*HD bf16
    unsigned short* packA1 = h0out + (size_t)MM * HD;          // 6291456 shorts
    float*          logits = (float*)packA1;                   // overlay (post-L1)
    unsigned short* packA0 = packA1 + 6291456;                 // 3145728 shorts
    unsigned char*  h1out  = (unsigned char*)packA0;           // 32MB overlay (post-L0)

    // zero: cnt (64 u32) + hbuf0 + hbuf1
    zero_kernel<<<512, 256, 0, stream>>>((float*)cnt, 64 + (131072 + 131072) / 2);

    pack_kernel<<<(3145728 + 255) / 256, 256, 0, stream>>>(w_ih0, w_hh0, packA0, EE, 24, 3145728);
    pack_kernel<<<(6291456 + 255) / 256, 256, 0, stream>>>(w_ih1, w_hh1, packA1, HD, 48, 6291456);

    bilstm_persist<0><<<256, 256, 0, stream>>>(
        ids, emb, nullptr, packA0, b_ih0, b_hh0, hbuf0, h0out, nullptr, cnt);
    bilstm_persist<1><<<256, 256, 0, stream>>>(
        ids, nullptr, h0out, packA1, b_ih1, b_hh1, hbuf1, nullptr, h1out, cnt + 32);

    logits_fp8<<<MM / 4, 256, 0, stream>>>(h1out, cls_w, logits);
    crf_kernel<<<BB, 64, 0, stream>>>(logits, labels, vlen, trans, start_t, end_t,
                                      cls_b, (float*)d_out, llh);
    loss_kernel<<<1, 64, 0, stream>>>(llh, (float*)d_out);
}